// Round 6
// baseline (840.278 us; speedup 1.0000x reference)
//
#include <hip/hip_runtime.h>
#include <hip/hip_cooperative_groups.h>
namespace cg = cooperative_groups;

#define NTOT   6422528   // 16*56*56*128
#define NPERB  401408    // 56*56*128
#define HH     56
#define WW     56
#define CC     128
#define NBLK   1024      // 4 blocks/CU * 256 CUs -- conservative cooperative residency
#define NTHR   256
#define GSZ    (NBLK*NTHR)   // 262144 threads

__device__ __forceinline__ float sigmoidf_fast(float x) {
    return 1.f / (1.f + __expf(-x));
}

// SAT box sum, window [i-hk+1, i+hk] x [j-hk+1, j+hk] (TF SAME padding, even k=2*hk)
__device__ __forceinline__ float boxsum(const float* __restrict__ p, int i, int j, int hk) {
    int y1 = min(i + hk, HH - 1);
    int y0 = i - hk;
    int x1 = min(j + hk, WW - 1);
    int x0 = j - hk;
    float s = p[(y1 * WW + x1) * CC];
    if (y0 >= 0)            s -= p[(y0 * WW + x1) * CC];
    if (x0 >= 0)            s -= p[(y1 * WW + x0) * CC];
    if (y0 >= 0 && x0 >= 0) s += p[(y0 * WW + x0) * CC];
    return fmaxf(s, 0.f);
}

// per-element gather math shared by coop + fallback
__device__ __forceinline__ void gather_elem(const float* __restrict__ sp, int i, int j,
                                            float d0, float d1, float d2, float d3, float d4,
                                            float nd, float g, float be, float bm, float rs,
                                            float xv, float xm, float xi,
                                            float& Aout, float& Bout, float& wout) {
    float l0 = __logf(boxsum(sp, i, j, 1)  + 1e-7f);
    float l1 = __logf(boxsum(sp, i, j, 2)  + 1e-7f);
    float l2 = __logf(boxsum(sp, i, j, 4)  + 1e-7f);
    float l3 = __logf(boxsum(sp, i, j, 8)  + 1e-7f);
    float l4 = __logf(boxsum(sp, i, j, 16) + 1e-7f);
    float w  = -2.f * l0 - l1 + l3 + 2.f * l4;
    wout = w;
    float alphas = w * 0.14426950408889634f;   // 1/(10*ln2)
    float mean = 0.2f * (l0 + l1 + l2 + l3 + l4);
    float a0 = l0 - mean, a1 = l1 - mean, a2 = l2 - mean, a3 = l3 - mean, a4 = l4 - mean;
    float na2  = a0 * a0 + a1 * a1 + a2 * a2 + a3 * a3 + a4 * a4;
    float adot = a0 * d0 + a1 * d1 + a2 * d2 + a3 * d3 + a4 * d4;
    float na = sqrtf(fmaxf(na2, 0.f));
    float cosv = (alphas * adot) / (na * fabsf(alphas) * nd + 1e-7f);
    float sim = 0.5f * (cosv + 1.f);
    float sbn = sigmoidf_fast(g * (alphas - bm) * rs + be);
    float xs = (xv - xm) * xi;
    Aout = sim * sbn;
    Bout = (1.f - sim) * xs;
}

__device__ __forceinline__ void kappa_consts(const float* kap, float* dcs) {
    float v[5]; float mean = 0.f;
    for (int s = 0; s < 5; s++) {
        float lr = 0.6931471805599453f * (float)(s + 1);
        float k_ = 1.f / (1.f + expf(-kap[s]));
        float lk = 1.f / (1.f + expf(-logf(k_ + 1e-7f)));
        v[s] = lk + lr; mean += v[s];
    }
    mean *= 0.2f; float nd = 0.f;
    for (int s = 0; s < 5; s++) { float d = v[s] - mean; dcs[s] = d; nd += d * d; }
    dcs[5] = sqrtf(nd);
}

// ================= cooperative mega-kernel =================
__launch_bounds__(NTHR, 4)
__global__ void k_mega(const float* __restrict__ x,   const float* __restrict__ kap,
                       const float* __restrict__ W1,  const float* __restrict__ b1,
                       const float* __restrict__ W2,  const float* __restrict__ b2,
                       const float* __restrict__ gam, const float* __restrict__ bet,
                       const float* __restrict__ bnm, const float* __restrict__ bnv,
                       float* __restrict__ SAT, float* __restrict__ A, float* __restrict__ Bb,
                       float* __restrict__ sq,  float* __restrict__ bmn, float* __restrict__ bmx,
                       float* __restrict__ dcs, float* __restrict__ out)
{
    cg::grid_group grid = cg::this_grid();
    const int tid = threadIdx.x;
    const int p   = blockIdx.x;

    __shared__ float buf[2048];          // SE squeeze / excite
    __shared__ float hid[256];
    __shared__ float red[256], red2[256];
    __shared__ float sxm, sxi;

    // ---------- P0: per-block min/max partials (64 blocks/sample) ----------
    {
        int b = p >> 6, seg = p & 63;
        const float4* xp = (const float4*)x + b * (NPERB / 4) + seg * 1568;
        float mn = 3.4e38f, mx = -3.4e38f;
        for (int v = tid; v < 1568; v += NTHR) {
            float4 q = xp[v];
            mn = fminf(mn, fminf(fminf(q.x, q.y), fminf(q.z, q.w)));
            mx = fmaxf(mx, fmaxf(fmaxf(q.x, q.y), fmaxf(q.z, q.w)));
        }
        red[tid] = mn; red2[tid] = mx;
        __syncthreads();
        for (int s = 128; s > 0; s >>= 1) {
            if (tid < s) {
                red[tid]  = fminf(red[tid],  red[tid + s]);
                red2[tid] = fmaxf(red2[tid], red2[tid + s]);
            }
            __syncthreads();
        }
        if (tid == 0) { bmn[p] = red[0]; bmx[p] = red2[0]; }
        if (p == 0) {
            for (int k = tid; k < 2048; k += NTHR) sq[k] = 0.f;
            if (tid == 0) kappa_consts(kap, dcs);
        }
        __syncthreads();
    }
    grid.sync();  // S1

    // redundant per-block decode of one sample's min/max (block-uniform b!)
    auto decode = [&](int b) {
        float mn = 3.4e38f, mx = -3.4e38f;
        if (tid < 64) { mn = bmn[b * 64 + tid]; mx = bmx[b * 64 + tid]; }
        __syncthreads();                 // red reuse guard
        red[tid] = mn; red2[tid] = mx;
        __syncthreads();
        for (int s = 128; s > 0; s >>= 1) {
            if (tid < s) {
                red[tid]  = fminf(red[tid],  red[tid + s]);
                red2[tid] = fmaxf(red2[tid], red2[tid + s]);
            }
            __syncthreads();
        }
        if (tid == 0) { sxm = red[0]; sxi = 1.f / (red2[0] - red[0] + 1e-7f); }
        __syncthreads();
    };

    float v[28];   // segment scan values, live across grid syncs
    const int c   = tid & 127;
    const int seg = tid >> 7;            // 0 or 1, depth-28 segments

    // ---------- P1a: column prefix partials  (block p = (b,j), p<896) ----------
    if (p < 896) {
        int b = p / 56, j = p % 56;
        decode(b);
        float xm = sxm, xi = sxi;
        int base = b * NPERB + j * 128 + c + seg * 28 * 7168;
        float acc = 0.f;
#pragma unroll
        for (int k = 0; k < 28; k++) { acc += (x[base + k * 7168] - xm) * xi; v[k] = acc; }
        A[p * 256 + tid] = acc;          // A reused as partial scratch
    }
    grid.sync();  // S2
    // ---------- P1b: add segment base, write column-SAT ----------
    if (p < 896) {
        int b = p / 56, j = p % 56;
        float basev = (seg == 1) ? A[p * 256 + c] : 0.f;
        int base = b * NPERB + j * 128 + c + seg * 28 * 7168;
#pragma unroll
        for (int k = 0; k < 28; k++) SAT[base + k * 7168] = basev + v[k];
    }
    grid.sync();  // S3

    // ---------- P2a: row prefix partials  (block p = (b,i)) ----------
    if (p < 896) {
        int b = p / 56, i = p % 56;
        int base = b * NPERB + i * 7168 + c + seg * 28 * 128;
        float acc = 0.f;
#pragma unroll
        for (int k = 0; k < 28; k++) { acc += SAT[base + k * 128]; v[k] = acc; }
        A[p * 256 + tid] = acc;
    }
    grid.sync();  // S4
    // ---------- P2b: write full SAT in place ----------
    if (p < 896) {
        int b = p / 56, i = p % 56;
        float basev = (seg == 1) ? A[p * 256 + c] : 0.f;
        int base = b * NPERB + i * 7168 + c + seg * 28 * 128;
#pragma unroll
        for (int k = 0; k < 28; k++) SAT[base + k * 128] = basev + v[k];
    }
    grid.sync();  // S5

    // ---------- P3: gather + A/B emit + squeeze (3584 units over 1024 blocks) ----------
    {
        float d0 = dcs[0], d1 = dcs[1], d2 = dcs[2], d3 = dcs[3], d4 = dcs[4], nd = dcs[5];
        int half = tid >> 7;
        float g  = gam[c], be = bet[c], bm = bnm[c];
        float rs = rsqrtf(bnv[c] + 1e-3f);
        int k8 = p & 7, m = p >> 3;      // XCD slab swizzle: XCD k8 -> 2-sample slab
        for (int kk = 0; kk < 4; kk++) {
            int off = m + kk * 128;
            if (off < 448) {
                int L = k8 * 448 + off;
                int b = L / 224, rem = L % 224;
                int i = rem >> 2, q = rem & 3;
                decode(b);               // block-uniform
                float xm = sxm, xi = sxi;
                const float* sp = SAT + b * NPERB + c;
                float asum = 0.f;
                int j0 = q * 14 + half * 7;
                for (int jj = 0; jj < 7; jj++) {
                    int j = j0 + jj;
                    int idx = b * NPERB + i * 7168 + j * 128 + c;
                    float Av, Bv, w;
                    gather_elem(sp, i, j, d0, d1, d2, d3, d4, nd, g, be, bm, rs,
                                x[idx], xm, xi, Av, Bv, w);
                    A[idx] = Av; Bb[idx] = Bv;
                    asum += w;
                }
                asum *= 0.14426950408889634f;
                red[tid] = asum;
                __syncthreads();
                if (tid < 128)
                    atomicAdd(&sq[b * 128 + tid], red[tid] + red[tid + 128]);
                __syncthreads();         // red reuse guard (next decode)
            }
        }
    }
    grid.sync();  // S6

    // ---------- P4: SE MLP (redundant per block), excite -> LDS ----------
    {
        for (int k = tid; k < 2048; k += NTHR) buf[k] = sq[k] * (1.f / 3136.f);
        __syncthreads();
        {
            int bb = tid >> 4, h = tid & 15;
            float acc = b1[h];
            for (int c2 = 0; c2 < 128; c2++) acc += buf[bb * 128 + c2] * W1[c2 * 16 + h];
            hid[bb * 16 + h] = fmaxf(acc, 0.f);
        }
        __syncthreads();
        for (int k = tid; k < 2048; k += NTHR) {
            int bb = k >> 7, c2 = k & 127;
            float acc = b2[c2];
#pragma unroll
            for (int h = 0; h < 16; h++) acc += hid[bb * 16 + h] * W2[h * 128 + c2];
            buf[k] = sigmoidf_fast(acc);
        }
        __syncthreads();
    }

    // ---------- P5: mix out = A + B * excite ----------
    {
        const float4* Ap = (const float4*)A;
        const float4* Bp = (const float4*)Bb;
        float4* op = (float4*)out;
        int t = p * NTHR + tid;
        for (int f4 = t; f4 < NTOT / 4; f4 += GSZ) {
            int flat = f4 * 4;
            int b  = flat / NPERB;
            int cb = flat & 127;
            float4 a = Ap[f4], bv = Bp[f4];
            op[f4] = make_float4(a.x + bv.x * buf[b * 128 + cb],
                                 a.y + bv.y * buf[b * 128 + cb + 1],
                                 a.z + bv.z * buf[b * 128 + cb + 2],
                                 a.w + bv.w * buf[b * 128 + cb + 3]);
        }
    }
}

// ================= fallback path (proven R4 structure, f32) =================
__global__ void fk_minmax(const float* __restrict__ x, float* __restrict__ mnp, float* __restrict__ mxp) {
    int b = blockIdx.x >> 6, nb = blockIdx.x & 63;
    const float4* p = (const float4*)(x + b * NPERB + nb * 6272);
    float mn = 3.4e38f, mx = -3.4e38f;
    for (int v = threadIdx.x; v < 1568; v += 256) {
        float4 q = p[v];
        mn = fminf(mn, fminf(fminf(q.x, q.y), fminf(q.z, q.w)));
        mx = fmaxf(mx, fmaxf(fmaxf(q.x, q.y), fmaxf(q.z, q.w)));
    }
#pragma unroll
    for (int off = 32; off >= 1; off >>= 1) {
        mn = fminf(mn, __shfl_xor(mn, off));
        mx = fmaxf(mx, __shfl_xor(mx, off));
    }
    __shared__ float smn[4], smx[4];
    int wid = threadIdx.x >> 6;
    if ((threadIdx.x & 63) == 0) { smn[wid] = mn; smx[wid] = mx; }
    __syncthreads();
    if (threadIdx.x == 0) {
        mnp[blockIdx.x] = fminf(fminf(smn[0], smn[1]), fminf(smn[2], smn[3]));
        mxp[blockIdx.x] = fmaxf(fmaxf(smx[0], smx[1]), fmaxf(smx[2], smx[3]));
    }
}

__global__ void fk_prep(const float* __restrict__ kap, const float* __restrict__ mnp,
                        const float* __restrict__ mxp, float* __restrict__ xmn,
                        float* __restrict__ xiv, float* __restrict__ dcs, float* __restrict__ sq) {
    int t = threadIdx.x;
    for (int k = t; k < 2048; k += 256) sq[k] = 0.f;
    if (t < 16) {
        float mn = 3.4e38f, mx = -3.4e38f;
        for (int k = 0; k < 64; k++) {
            mn = fminf(mn, mnp[t * 64 + k]);
            mx = fmaxf(mx, mxp[t * 64 + k]);
        }
        xmn[t] = mn;
        xiv[t] = 1.f / (mx - mn + 1e-7f);
    } else if (t == 32) kappa_consts(kap, dcs);
}

__global__ void fk_colsum(const float* __restrict__ x, float* __restrict__ SAT,
                          const float* __restrict__ xmn, const float* __restrict__ xiv) {
    int t = blockIdx.x * 256 + threadIdx.x;
    int b = t / 7168, r = t % 7168;
    float xm = xmn[b], xi = xiv[b];
    int base = b * NPERB + r;
    float acc = 0.f;
    for (int i = 0; i < HH; i++) {
        acc += (x[base + i * 7168] - xm) * xi;
        SAT[base + i * 7168] = acc;
    }
}

__global__ void fk_rowsum(float* __restrict__ SAT) {
    int t = blockIdx.x * 256 + threadIdx.x;
    int b = t / 7168, r = t % 7168;
    int i = r >> 7, cc = r & 127;
    int base = b * NPERB + i * 7168 + cc;
    float acc = 0.f;
    for (int j = 0; j < WW; j++) {
        acc += SAT[base + j * 128];
        SAT[base + j * 128] = acc;
    }
}

__global__ void fk_gather(const float* __restrict__ SAT, const float* __restrict__ x,
                          const float* __restrict__ gam, const float* __restrict__ bet,
                          const float* __restrict__ bnm, const float* __restrict__ bnv,
                          const float* __restrict__ xmn, const float* __restrict__ xiv,
                          const float* __restrict__ dcs, float* __restrict__ sq,
                          float* __restrict__ A, float* __restrict__ Bb) {
    int p_ = blockIdx.x;                    // 3584 blocks
    int L  = (p_ & 7) * 448 + (p_ >> 3);
    int b = L / 224, rem = L % 224;
    int i = rem >> 2, q = rem & 3;
    int c = threadIdx.x & 127, half = threadIdx.x >> 7;
    const float* sp = SAT + b * NPERB + c;
    float g = gam[c], be = bet[c], bm = bnm[c];
    float rs = rsqrtf(bnv[c] + 1e-3f);
    float xm = xmn[b], xi = xiv[b];
    float d0 = dcs[0], d1 = dcs[1], d2 = dcs[2], d3 = dcs[3], d4 = dcs[4], nd = dcs[5];
    float asum = 0.f;
    int j0 = q * 14 + half * 7;
    for (int jj = 0; jj < 7; jj++) {
        int j = j0 + jj;
        int idx = b * NPERB + i * 7168 + j * 128 + c;
        float Av, Bv, w;
        gather_elem(sp, i, j, d0, d1, d2, d3, d4, nd, g, be, bm, rs, x[idx], xm, xi, Av, Bv, w);
        A[idx] = Av; Bb[idx] = Bv;
        asum += w;
    }
    asum *= 0.14426950408889634f;
    __shared__ float red[256];
    red[threadIdx.x] = asum;
    __syncthreads();
    if (threadIdx.x < 128)
        atomicAdd(&sq[b * 128 + threadIdx.x], red[threadIdx.x] + red[threadIdx.x + 128]);
}

__global__ void fk_se(const float* __restrict__ sq, const float* __restrict__ W1,
                      const float* __restrict__ b1, const float* __restrict__ W2,
                      const float* __restrict__ b2, float* __restrict__ exc) {
    __shared__ float sqs[2048];
    __shared__ float hid[256];
    int t = threadIdx.x;
    for (int k = t; k < 2048; k += 256) sqs[k] = sq[k] * (1.f / 3136.f);
    __syncthreads();
    {
        int b = t >> 4, h = t & 15;
        float acc = b1[h];
        for (int c2 = 0; c2 < 128; c2++) acc += sqs[b * 128 + c2] * W1[c2 * 16 + h];
        hid[b * 16 + h] = fmaxf(acc, 0.f);
    }
    __syncthreads();
    for (int k = t; k < 2048; k += 256) {
        int b = k >> 7, c2 = k & 127;
        float acc = b2[c2];
#pragma unroll
        for (int h = 0; h < 16; h++) acc += hid[b * 16 + h] * W2[h * 128 + c2];
        exc[k] = sigmoidf_fast(acc);
    }
}

__global__ void fk_mix(const float* __restrict__ A, const float* __restrict__ Bb,
                       const float* __restrict__ exc, float* __restrict__ out) {
    int t = blockIdx.x * 256 + threadIdx.x;
    int flat = t * 4;
    int b = flat / NPERB, cb = flat & 127;
    float4 a = ((const float4*)A)[t];
    float4 bv = ((const float4*)Bb)[t];
    ((float4*)out)[t] = make_float4(a.x + bv.x * exc[b * 128 + cb],
                                    a.y + bv.y * exc[b * 128 + cb + 1],
                                    a.z + bv.z * exc[b * 128 + cb + 2],
                                    a.w + bv.w * exc[b * 128 + cb + 3]);
}

extern "C" void kernel_launch(void* const* d_in, const int* in_sizes, int n_in,
                              void* d_out, int out_size, void* d_ws, size_t ws_size,
                              hipStream_t stream) {
    const float* x   = (const float*)d_in[0];
    const float* kap = (const float*)d_in[1];
    const float* W1  = (const float*)d_in[2];
    const float* b1  = (const float*)d_in[3];
    const float* W2  = (const float*)d_in[4];
    const float* b2  = (const float*)d_in[5];
    const float* gam = (const float*)d_in[6];
    const float* bet = (const float*)d_in[7];
    const float* bnm = (const float*)d_in[8];
    const float* bnv = (const float*)d_in[9];
    float* out = (float*)d_out;

    float* SAT = (float*)d_ws;       // NTOT
    float* A   = SAT + NTOT;         // NTOT (also prefix-partial scratch)
    float* Bb  = A + NTOT;           // NTOT
    float* sq  = Bb + NTOT;          // 2048
    float* bmn = sq + 2048;          // 1024  (fallback: mnp)
    float* bmx = bmn + 1024;         // 1024  (fallback: mxp)
    float* dcs = bmx + 1024;         // 8
    float* xmn = dcs + 8;            // 16    (fallback only)
    float* xiv = xmn + 16;           // 16
    float* exc = xiv + 16;           // 2048  (fallback only)

    void* args[] = { &x, &kap, &W1, &b1, &W2, &b2, &gam, &bet, &bnm, &bnv,
                     &SAT, &A, &Bb, &sq, &bmn, &bmx, &dcs, &out };
    hipError_t err = hipLaunchCooperativeKernel((const void*)k_mega, dim3(NBLK), dim3(NTHR),
                                                args, 0, stream);
    if (err == hipSuccess) return;
    (void)hipGetLastError();   // clear sticky error, use proven multi-kernel path

    fk_minmax<<<1024, 256, 0, stream>>>(x, bmn, bmx);
    fk_prep<<<1, 256, 0, stream>>>(kap, bmn, bmx, xmn, xiv, dcs, sq);
    fk_colsum<<<448, 256, 0, stream>>>(x, SAT, xmn, xiv);
    fk_rowsum<<<448, 256, 0, stream>>>(SAT);
    fk_gather<<<3584, 256, 0, stream>>>(SAT, x, gam, bet, bnm, bnv, xmn, xiv, dcs, sq, A, Bb);
    fk_se<<<1, 256, 0, stream>>>(sq, W1, b1, W2, b2, exc);
    fk_mix<<<6272, 256, 0, stream>>>(A, Bb, exc, out);
}

// Round 7
// 186.086 us; speedup vs baseline: 4.5155x; 4.5155x over previous
//
#include <hip/hip_runtime.h>

#define NTOT   6422528   // 16*56*56*128
#define NPERB  401408    // 56*56*128
#define HH     56
#define WW     56
#define CC     128
#define ROWP   228       // LDS row pitch: 56*4 + 4 pad floats (bank-conflict-free)

__device__ __forceinline__ float sigmoidf_fast(float x) {
    return __builtin_amdgcn_rcpf(1.f + __expf(-x));
}

__device__ __forceinline__ void kappa_consts(const float* kap, float* dcs) {
    float v[5]; float mean = 0.f;
    for (int s = 0; s < 5; s++) {
        float lr = 0.6931471805599453f * (float)(s + 1);
        float k_ = 1.f / (1.f + expf(-kap[s]));
        float lk = 1.f / (1.f + expf(-logf(k_ + 1e-7f)));
        v[s] = lk + lr; mean += v[s];
    }
    mean *= 0.2f; float nd = 0.f;
    for (int s = 0; s < 5; s++) { float d = v[s] - mean; dcs[s] = d; nd += d * d; }
    dcs[5] = sqrtf(nd);
}

// measure from RAW-x SAT: m = (boxsum_raw - xmin*validcnt) * xinv, clamped >= 0.
// Window rows (y0, y1], cols (x0, x1] with implicit zero row/col (TF SAME, even k=2*hk).
__device__ __forceinline__ float measure(const float* __restrict__ p, int i, int j, int hk,
                                         float xm, float xi) {
    int y1 = min(i + hk, HH - 1);
    int y0 = i - hk;
    int x1 = min(j + hk, WW - 1);
    int x0 = j - hk;
    float s = p[(y1 * WW + x1) * CC];
    if (y0 >= 0)            s -= p[(y0 * WW + x1) * CC];
    if (x0 >= 0)            s -= p[(y1 * WW + x0) * CC];
    if (y0 >= 0 && x0 >= 0) s += p[(y0 * WW + x0) * CC];
    float cnt = (float)((y1 - max(y0, -1)) * (x1 - max(x0, -1)));
    return fmaxf((s - xm * cnt) * xi, 0.f);
}

// ---------- K1: fused SAT build (raw x) + per-slab min/max partials ----------
// 512 blocks: XCD k (p%8) handles samples 2k,2k+1 entirely -> L2-local 16B reads.
// Each block: one (sample, 4-channel) slab -> LDS, col+row prefix, write SAT.
__global__ void k_sat(const float* __restrict__ x, float* __restrict__ SAT,
                      float* __restrict__ pmn, float* __restrict__ pmx) {
    __shared__ float sl[HH * ROWP];          // 51,072 B
    __shared__ float rmn[256], rmx[256];
    const int tid = threadIdx.x;
    int p = blockIdx.x;
    int k8 = p & 7, local = p >> 3;
    int b  = 2 * k8 + (local >> 5);
    int cg = local & 31;                      // 4-channel group
    const float4* xp = (const float4*)(x + b * NPERB + cg * 4);
    float mn = 3.4e38f, mx = -3.4e38f;
    for (int cell = tid; cell < 3136; cell += 256) {
        float4 q = xp[cell * 32];             // (i*56+j)*128 + c4 : 16B granule
        int i = cell / 56, j = cell - i * 56;
        *(float4*)&sl[i * ROWP + j * 4] = q;
        mn = fminf(mn, fminf(fminf(q.x, q.y), fminf(q.z, q.w)));
        mx = fmaxf(mx, fmaxf(fmaxf(q.x, q.y), fmaxf(q.z, q.w)));
    }
    rmn[tid] = mn; rmx[tid] = mx;
    __syncthreads();
    for (int s = 128; s > 0; s >>= 1) {
        if (tid < s) {
            rmn[tid] = fminf(rmn[tid], rmn[tid + s]);
            rmx[tid] = fmaxf(rmx[tid], rmx[tid + s]);
        }
        __syncthreads();
    }
    if (tid == 0) { pmn[b * 32 + cg] = rmn[0]; pmx[b * 32 + cg] = rmx[0]; }
    // column prefix over i: unit u=tid<224 -> (j=u>>2, cc=u&3), addr = i*ROWP + u
    if (tid < 224) {
        float acc = 0.f;
        for (int i = 0; i < HH; i++) {
            acc += sl[i * ROWP + tid];
            sl[i * ROWP + tid] = acc;
        }
    }
    __syncthreads();
    // row prefix over j: unit u=tid<224 -> (i=u>>2, cc=u&3)
    if (tid < 224) {
        int base = (tid >> 2) * ROWP + (tid & 3);
        float acc = 0.f;
        for (int j = 0; j < WW; j++) {
            acc += sl[base + j * 4];
            sl[base + j * 4] = acc;
        }
    }
    __syncthreads();
    float4* sp = (float4*)(SAT + b * NPERB + cg * 4);
    for (int cell = tid; cell < 3136; cell += 256) {
        int i = cell / 56, j = cell - i * 56;
        sp[cell * 32] = *(float4*)&sl[i * ROWP + j * 4];
    }
}

// ---------- K2: finalize min/max, kappa constants, zero squeeze ----------
__global__ void k_prep(const float* __restrict__ kap, const float* __restrict__ pmn,
                       const float* __restrict__ pmx, float* __restrict__ xmn,
                       float* __restrict__ xiv, float* __restrict__ dcs, float* __restrict__ sq) {
    int t = threadIdx.x;
    for (int k = t; k < 2048; k += 256) sq[k] = 0.f;
    if (t < 16) {
        float mn = 3.4e38f, mx = -3.4e38f;
        for (int k = 0; k < 32; k++) {
            mn = fminf(mn, pmn[t * 32 + k]);
            mx = fmaxf(mx, pmx[t * 32 + k]);
        }
        xmn[t] = mn;
        xiv[t] = 1.f / (mx - mn + 1e-7f);
    } else if (t == 32) kappa_consts(kap, dcs);
}

// ---------- K3: gather + A/B emit + squeeze (proven R4 structure) ----------
__global__ void k_gather(const float* __restrict__ SAT, const float* __restrict__ x,
                         const float* __restrict__ gam, const float* __restrict__ bet,
                         const float* __restrict__ bnm, const float* __restrict__ bnv,
                         const float* __restrict__ xmn, const float* __restrict__ xiv,
                         const float* __restrict__ dcs, float* __restrict__ sq,
                         float* __restrict__ A, float* __restrict__ Bb) {
    int p_ = blockIdx.x;                    // 3584 blocks, XCD slab swizzle
    int L  = (p_ & 7) * 448 + (p_ >> 3);
    int b = L / 224, rem = L % 224;
    int i = rem >> 2, q = rem & 3;
    int c = threadIdx.x & 127, half = threadIdx.x >> 7;
    const float* sp = SAT + b * NPERB + c;
    float g = gam[c], be = bet[c], bm = bnm[c];
    float rs = rsqrtf(bnv[c] + 1e-3f);
    float xm = xmn[b], xi = xiv[b];
    float d0 = dcs[0], d1 = dcs[1], d2 = dcs[2], d3 = dcs[3], d4 = dcs[4], nd = dcs[5];
    float asum = 0.f;
    int j0 = q * 14 + half * 7;
    for (int jj = 0; jj < 7; jj++) {
        int j = j0 + jj;
        float l0 = __logf(measure(sp, i, j, 1,  xm, xi) + 1e-7f);
        float l1 = __logf(measure(sp, i, j, 2,  xm, xi) + 1e-7f);
        float l2 = __logf(measure(sp, i, j, 4,  xm, xi) + 1e-7f);
        float l3 = __logf(measure(sp, i, j, 8,  xm, xi) + 1e-7f);
        float l4 = __logf(measure(sp, i, j, 16, xm, xi) + 1e-7f);
        float w  = -2.f * l0 - l1 + l3 + 2.f * l4;
        asum += w;
        float alphas = w * 0.14426950408889634f;   // 1/(10*ln2)
        float mean = 0.2f * (l0 + l1 + l2 + l3 + l4);
        float a0 = l0 - mean, a1 = l1 - mean, a2 = l2 - mean, a3 = l3 - mean, a4 = l4 - mean;
        float na2  = a0 * a0 + a1 * a1 + a2 * a2 + a3 * a3 + a4 * a4;
        float adot = a0 * d0 + a1 * d1 + a2 * d2 + a3 * d3 + a4 * d4;
        float na = __builtin_amdgcn_sqrtf(na2);
        float cosv = (alphas * adot) * __builtin_amdgcn_rcpf(na * fabsf(alphas) * nd + 1e-7f);
        float sim = 0.5f * (cosv + 1.f);
        float sbn = sigmoidf_fast(g * (alphas - bm) * rs + be);
        int idx = b * NPERB + i * 7168 + j * 128 + c;
        float xs = (x[idx] - xm) * xi;
        A[idx]  = sim * sbn;
        Bb[idx] = (1.f - sim) * xs;
    }
    asum *= 0.14426950408889634f;
    __shared__ float red[256];
    red[threadIdx.x] = asum;
    __syncthreads();
    if (threadIdx.x < 128)
        atomicAdd(&sq[b * 128 + threadIdx.x], red[threadIdx.x] + red[threadIdx.x + 128]);
}

// ---------- K4: squeeze-and-excite MLP ----------
__global__ void k_se(const float* __restrict__ sq, const float* __restrict__ W1,
                     const float* __restrict__ b1, const float* __restrict__ W2,
                     const float* __restrict__ b2, float* __restrict__ exc) {
    __shared__ float sqs[2048];
    __shared__ float hid[256];
    int t = threadIdx.x;
    for (int k = t; k < 2048; k += 256) sqs[k] = sq[k] * (1.f / 3136.f);
    __syncthreads();
    {
        int b = t >> 4, h = t & 15;
        float acc = b1[h];
        for (int c2 = 0; c2 < 128; c2++) acc += sqs[b * 128 + c2] * W1[c2 * 16 + h];
        hid[b * 16 + h] = fmaxf(acc, 0.f);
    }
    __syncthreads();
    for (int k = t; k < 2048; k += 256) {
        int b = k >> 7, c2 = k & 127;
        float acc = b2[c2];
#pragma unroll
        for (int h = 0; h < 16; h++) acc += hid[b * 16 + h] * W2[h * 128 + c2];
        exc[k] = sigmoidf_fast(acc);
    }
}

// ---------- K5: mix out = A + B * excite ----------
__global__ void k_mix(const float* __restrict__ A, const float* __restrict__ Bb,
                      const float* __restrict__ exc, float* __restrict__ out) {
    int t = blockIdx.x * 256 + threadIdx.x;
    int flat = t * 4;
    int b = flat / NPERB, cb = flat & 127;
    float4 a = ((const float4*)A)[t];
    float4 bv = ((const float4*)Bb)[t];
    ((float4*)out)[t] = make_float4(a.x + bv.x * exc[b * 128 + cb],
                                    a.y + bv.y * exc[b * 128 + cb + 1],
                                    a.z + bv.z * exc[b * 128 + cb + 2],
                                    a.w + bv.w * exc[b * 128 + cb + 3]);
}

extern "C" void kernel_launch(void* const* d_in, const int* in_sizes, int n_in,
                              void* d_out, int out_size, void* d_ws, size_t ws_size,
                              hipStream_t stream) {
    const float* x   = (const float*)d_in[0];
    const float* kap = (const float*)d_in[1];
    const float* W1  = (const float*)d_in[2];
    const float* b1  = (const float*)d_in[3];
    const float* W2  = (const float*)d_in[4];
    const float* b2  = (const float*)d_in[5];
    const float* gam = (const float*)d_in[6];
    const float* bet = (const float*)d_in[7];
    const float* bnm = (const float*)d_in[8];
    const float* bnv = (const float*)d_in[9];
    float* out = (float*)d_out;

    float* SAT = (float*)d_ws;       // NTOT (raw-x SAT)
    float* A   = SAT + NTOT;         // NTOT
    float* Bb  = A + NTOT;           // NTOT
    float* sq  = Bb + NTOT;          // 2048
    float* pmn = sq + 2048;          // 512
    float* pmx = pmn + 512;          // 512
    float* xmn = pmx + 512;          // 16
    float* xiv = xmn + 16;           // 16
    float* dcs = xiv + 16;           // 8
    float* exc = dcs + 8;            // 2048

    k_sat<<<512, 256, 0, stream>>>(x, SAT, pmn, pmx);
    k_prep<<<1, 256, 0, stream>>>(kap, pmn, pmx, xmn, xiv, dcs, sq);
    k_gather<<<3584, 256, 0, stream>>>(SAT, x, gam, bet, bnm, bnv, xmn, xiv, dcs, sq, A, Bb);
    k_se<<<1, 256, 0, stream>>>(sq, W1, b1, W2, b2, exc);
    k_mix<<<6272, 256, 0, stream>>>(A, Bb, exc, out);
}

// Round 8
// 158.765 us; speedup vs baseline: 5.2926x; 1.1721x over previous
//
#include <hip/hip_runtime.h>
#include <hip/hip_fp16.h>

#define NTOT   6422528   // 16*56*56*128
#define NPERB  401408    // 56*56*128
#define HH     56
#define WW     56
#define CC     128
#define RS     7296      // guarded SAT row stride: 57*128
#define SB     415872    // guarded SAT per-sample: 57*57*128

__device__ __forceinline__ float sigmoidf_fast(float x) {
    return __builtin_amdgcn_rcpf(1.f + __expf(-x));
}

__device__ __forceinline__ void kappa_consts(const float* kap, float* dcs) {
    float v[5]; float mean = 0.f;
    for (int s = 0; s < 5; s++) {
        float lr = 0.6931471805599453f * (float)(s + 1);
        float k_ = 1.f / (1.f + expf(-kap[s]));
        float lk = 1.f / (1.f + expf(-logf(k_ + 1e-7f)));
        v[s] = lk + lr; mean += v[s];
    }
    mean *= 0.2f; float nd = 0.f;
    for (int s = 0; s < 5; s++) { float d = v[s] - mean; dcs[s] = d; nd += d * d; }
    dcs[5] = sqrtf(nd);
}

// ---------- K1: column prefix of RAW x into guarded SAT + fused min/max ----------
// Fully coalesced: consecutive threads -> consecutive c. 448 blocks.
__global__ void k_colsum(const float* __restrict__ x, float* __restrict__ S,
                         float* __restrict__ pmn, float* __restrict__ pmx) {
    int t = blockIdx.x * 256 + threadIdx.x;    // 114688
    int b = t / 7168, r = t % 7168;
    int jm1 = r >> 7, c = r & 127;
    int xbase = b * NPERB + jm1 * 128 + c;
    int scol  = b * SB + (jm1 + 1) * 128 + c;
    S[scol] = 0.f;                              // guard row i=0
    if (jm1 == 0) S[b * SB + c] = 0.f;          // guard corner (0,0)
    float mn = 3.4e38f, mx = -3.4e38f;
    float acc = 0.f;
    for (int i = 1; i <= HH; i++) {
        float xv = x[xbase + (i - 1) * 7168];
        mn = fminf(mn, xv); mx = fmaxf(mx, xv);
        acc += xv;
        S[scol + i * RS] = acc;
    }
    __shared__ float rmn[256], rmx[256];
    rmn[threadIdx.x] = mn; rmx[threadIdx.x] = mx;
    __syncthreads();
    for (int s = 128; s > 0; s >>= 1) {
        if (threadIdx.x < s) {
            rmn[threadIdx.x] = fminf(rmn[threadIdx.x], rmn[threadIdx.x + s]);
            rmx[threadIdx.x] = fmaxf(rmx[threadIdx.x], rmx[threadIdx.x + s]);
        }
        __syncthreads();
    }
    if (threadIdx.x == 0) { pmn[blockIdx.x] = rmn[0]; pmx[blockIdx.x] = rmx[0]; }
}

// ---------- K2: row prefix in place (449th block does prep) ----------
__global__ void k_rowsum(float* __restrict__ S, const float* __restrict__ kap,
                         const float* __restrict__ pmn, const float* __restrict__ pmx,
                         float* __restrict__ xmn, float* __restrict__ xiv,
                         float* __restrict__ dcs, float* __restrict__ sq) {
    if (blockIdx.x == 448) {                    // prep block
        int t = threadIdx.x;
        for (int k = t; k < 2048; k += 256) sq[k] = 0.f;
        if (t < 16) {
            float mn = 3.4e38f, mx = -3.4e38f;
            for (int k = 0; k < 28; k++) {      // 28 partials per sample
                mn = fminf(mn, pmn[t * 28 + k]);
                mx = fmaxf(mx, pmx[t * 28 + k]);
            }
            xmn[t] = mn;
            xiv[t] = 1.f / (mx - mn + 1e-7f);
        } else if (t == 32) kappa_consts(kap, dcs);
        return;
    }
    int t = blockIdx.x * 256 + threadIdx.x;
    int b = t / 7168, r = t % 7168;
    int i = (r >> 7) + 1, c = r & 127;          // rows 1..56
    int base = b * SB + i * RS + c;
    S[base] = 0.f;                              // guard col j=0
    float acc = 0.f;
    for (int j = 1; j <= WW; j++) {
        acc += S[base + j * 128];
        S[base + j * 128] = acc;
    }
}

// ---------- K3: gather + packed A/B emit + squeeze ----------
struct ScaleU { int rb1, rb0; float xmch; };

__global__ void k_gather(const float* __restrict__ S, const float* __restrict__ x,
                         const float* __restrict__ gam, const float* __restrict__ bet,
                         const float* __restrict__ bnm, const float* __restrict__ bnv,
                         const float* __restrict__ xmn, const float* __restrict__ xiv,
                         const float* __restrict__ dcs, float* __restrict__ sq,
                         unsigned int* __restrict__ ABu) {
    int p_ = blockIdx.x;                        // 3584 blocks, XCD slab swizzle
    int L  = (p_ & 7) * 448 + (p_ >> 3);
    int b = L / 224, rem = L % 224;
    int i = rem >> 2, q = rem & 3;
    int c = threadIdx.x & 127, half = threadIdx.x >> 7;
    const float* sp = S + b * SB + c;
    float g = gam[c], be = bet[c], bm = bnm[c];
    float rs = rsqrtf(bnv[c] + 1e-3f);
    float xm = xmn[b], xi = xiv[b];
    float d0 = dcs[0], d1 = dcs[1], d2 = dcs[2], d3 = dcs[3], d4 = dcs[4], nd = dcs[5];

    // block-uniform per-scale row constants (land in SGPRs)
    auto mkU = [&](int hk) {
        ScaleU u;
        int y1g = min(i + hk, HH - 1) + 1;
        int y0g = max(i - hk + 1, 0);
        u.rb1 = y1g * RS; u.rb0 = y0g * RS;
        u.xmch = xm * (float)(y1g - y0g);
        return u;
    };
    ScaleU u0 = mkU(1), u1 = mkU(2), u2 = mkU(4), u3 = mkU(8), u4 = mkU(16);

    auto meas = [&](int j, const ScaleU& u, int hk) -> float {
        int x1g = min(j + hk, WW - 1) + 1;
        int x0g = max(j - hk + 1, 0);
        float cw = (float)(x1g - x0g);
        int o1 = x1g << 7, o0 = x0g << 7;
        float s = sp[u.rb1 + o1] - sp[u.rb0 + o1] - sp[u.rb1 + o0] + sp[u.rb0 + o0];
        return __logf(fmaxf((s - u.xmch * cw) * xi, 0.f) + 1e-7f);
    };

    float asum = 0.f;
    int j0 = q * 14 + half * 7;
    for (int jj = 0; jj < 7; jj++) {
        int j = j0 + jj;
        float l0 = meas(j, u0, 1);
        float l1 = meas(j, u1, 2);
        float l2 = meas(j, u2, 4);
        float l3 = meas(j, u3, 8);
        float l4 = meas(j, u4, 16);
        float w  = -2.f * l0 - l1 + l3 + 2.f * l4;
        asum += w;
        float alphas = w * 0.14426950408889634f;   // 1/(10*ln2)
        float mean = 0.2f * (l0 + l1 + l2 + l3 + l4);
        float a0 = l0 - mean, a1 = l1 - mean, a2 = l2 - mean, a3 = l3 - mean, a4 = l4 - mean;
        float na2  = a0 * a0 + a1 * a1 + a2 * a2 + a3 * a3 + a4 * a4;
        float adot = a0 * d0 + a1 * d1 + a2 * d2 + a3 * d3 + a4 * d4;
        float na = __builtin_amdgcn_sqrtf(na2);
        float cosv = (alphas * adot) * __builtin_amdgcn_rcpf(na * fabsf(alphas) * nd + 1e-7f);
        float sim = 0.5f * (cosv + 1.f);
        float sbn = sigmoidf_fast(g * (alphas - bm) * rs + be);
        int idx = b * NPERB + i * 7168 + j * 128 + c;
        float xs = (x[idx] - xm) * xi;
        float A = sim * sbn;
        float B = (1.f - sim) * xs;
        __half2 h2 = __floats2half2_rn(A, B);
        ABu[idx] = __builtin_bit_cast(unsigned int, h2);
    }
    asum *= 0.14426950408889634f;
    __shared__ float red[256];
    red[threadIdx.x] = asum;
    __syncthreads();
    if (threadIdx.x < 128)
        atomicAdd(&sq[b * 128 + threadIdx.x], red[threadIdx.x] + red[threadIdx.x + 128]);
}

// ---------- K4: squeeze-and-excite MLP ----------
__global__ void k_se(const float* __restrict__ sq, const float* __restrict__ W1,
                     const float* __restrict__ b1, const float* __restrict__ W2,
                     const float* __restrict__ b2, float* __restrict__ exc) {
    __shared__ float sqs[2048];
    __shared__ float hid[256];
    int t = threadIdx.x;
    for (int k = t; k < 2048; k += 256) sqs[k] = sq[k] * (1.f / 3136.f);
    __syncthreads();
    {
        int b = t >> 4, h = t & 15;
        float acc = b1[h];
        for (int c2 = 0; c2 < 128; c2++) acc += sqs[b * 128 + c2] * W1[c2 * 16 + h];
        hid[b * 16 + h] = fmaxf(acc, 0.f);
    }
    __syncthreads();
    for (int k = t; k < 2048; k += 256) {
        int b = k >> 7, c2 = k & 127;
        float acc = b2[c2];
#pragma unroll
        for (int h = 0; h < 16; h++) acc += hid[b * 16 + h] * W2[h * 128 + c2];
        exc[k] = sigmoidf_fast(acc);
    }
}

// ---------- K5: mix out = A + B * excite ----------
__global__ void k_mix(const unsigned int* __restrict__ ABu,
                      const float* __restrict__ exc, float* __restrict__ out) {
    int t = blockIdx.x * 256 + threadIdx.x;    // 1,605,632 groups of 4
    int flat = t * 4;
    int b = flat / NPERB, cb = flat & 127;
    uint4 u = ((const uint4*)ABu)[t];
    float4 e = *(const float4*)(exc + b * 128 + cb);
    float2 p0 = __half22float2(__builtin_bit_cast(__half2, u.x));
    float2 p1 = __half22float2(__builtin_bit_cast(__half2, u.y));
    float2 p2 = __half22float2(__builtin_bit_cast(__half2, u.z));
    float2 p3 = __half22float2(__builtin_bit_cast(__half2, u.w));
    ((float4*)out)[t] = make_float4(p0.x + p0.y * e.x,
                                    p1.x + p1.y * e.y,
                                    p2.x + p2.y * e.z,
                                    p3.x + p3.y * e.w);
}

extern "C" void kernel_launch(void* const* d_in, const int* in_sizes, int n_in,
                              void* d_out, int out_size, void* d_ws, size_t ws_size,
                              hipStream_t stream) {
    const float* x   = (const float*)d_in[0];
    const float* kap = (const float*)d_in[1];
    const float* W1  = (const float*)d_in[2];
    const float* b1  = (const float*)d_in[3];
    const float* W2  = (const float*)d_in[4];
    const float* b2  = (const float*)d_in[5];
    const float* gam = (const float*)d_in[6];
    const float* bet = (const float*)d_in[7];
    const float* bnm = (const float*)d_in[8];
    const float* bnv = (const float*)d_in[9];
    float* out = (float*)d_out;

    float*        S   = (float*)d_ws;            // 16*SB guarded SAT
    unsigned int* ABu = (unsigned int*)(S + 16 * SB);  // NTOT u32 (half2 A,B)
    float* sq  = (float*)(ABu + NTOT);           // 2048
    float* pmn = sq + 2048;                      // 448 -> 512
    float* pmx = pmn + 512;                      // 512
    float* xmn = pmx + 512;                      // 16
    float* xiv = xmn + 16;                       // 16
    float* dcs = xiv + 16;                       // 8
    float* exc = dcs + 8;                        // 2048

    k_colsum<<<448, 256, 0, stream>>>(x, S, pmn, pmx);
    k_rowsum<<<449, 256, 0, stream>>>(S, kap, pmn, pmx, xmn, xiv, dcs, sq);
    k_gather<<<3584, 256, 0, stream>>>(S, x, gam, bet, bnm, bnv, xmn, xiv, dcs, sq, ABu);
    k_se<<<1, 256, 0, stream>>>(sq, W1, b1, W2, b2, exc);
    k_mix<<<6272, 256, 0, stream>>>(ABu, exc, out);
}

// Round 9
// 152.778 us; speedup vs baseline: 5.5000x; 1.0392x over previous
//
#include <hip/hip_runtime.h>
#include <hip/hip_fp16.h>

#define NTOT   6422528   // 16*56*56*128
#define NPERB  401408    // 56*56*128
#define HH     56
#define WW     56
#define CC     128
#define RS     7296      // guarded SAT row stride: 57*128
#define SB     415872    // guarded SAT per-sample: 57*57*128
#define LOG2E  1.4426950408889634f

__device__ __forceinline__ float sigmoidf_fast(float x) {
    return __builtin_amdgcn_rcpf(1.f + __expf(-x));
}

__device__ __forceinline__ void kappa_consts(const float* kap, float* dcs) {
    float v[5]; float mean = 0.f;
    for (int s = 0; s < 5; s++) {
        float lr = 0.6931471805599453f * (float)(s + 1);
        float k_ = 1.f / (1.f + expf(-kap[s]));
        float lk = 1.f / (1.f + expf(-logf(k_ + 1e-7f)));
        v[s] = lk + lr; mean += v[s];
    }
    mean *= 0.2f; float nd = 0.f;
    for (int s = 0; s < 5; s++) { float d = v[s] - mean; dcs[s] = d; nd += d * d; }
    dcs[5] = sqrtf(nd);
}

// ---------- K1: segmented column prefix (depth 28) + fused min/max ----------
// 896 blocks: block = (b, j). tid: c = tid&127, seg = tid>>7.
__global__ void k_colsum(const float* __restrict__ x, float* __restrict__ S,
                         float* __restrict__ pmn, float* __restrict__ pmx) {
    int p = blockIdx.x;
    int b = p / 56, j = p % 56;
    int c = threadIdx.x & 127, seg = threadIdx.x >> 7;
    int xbase = b * NPERB + j * 128 + c;
    int scol  = b * SB + (j + 1) * 128 + c;
    __shared__ float tot[128];
    __shared__ float rmn[256], rmx[256];
    float mn = 3.4e38f, mx = -3.4e38f;
    float v[28];
    if (seg == 0) {
        S[scol] = 0.f;                          // guard row i=0
        if (j == 0) S[b * SB + c] = 0.f;        // guard corner (0,0)
        float acc = 0.f;
#pragma unroll
        for (int k = 0; k < 28; k++) {
            float xv = x[xbase + k * 7168];
            mn = fminf(mn, xv); mx = fmaxf(mx, xv);
            acc += xv;
            S[scol + (k + 1) * RS] = acc;
        }
        tot[c] = acc;
    } else {
        float acc = 0.f;
#pragma unroll
        for (int k = 0; k < 28; k++) {
            float xv = x[xbase + (28 + k) * 7168];
            mn = fminf(mn, xv); mx = fmaxf(mx, xv);
            acc += xv;
            v[k] = acc;
        }
    }
    __syncthreads();
    if (seg == 1) {
        float base = tot[c];
#pragma unroll
        for (int k = 0; k < 28; k++) S[scol + (29 + k) * RS] = base + v[k];
    }
    rmn[threadIdx.x] = mn; rmx[threadIdx.x] = mx;
    __syncthreads();
    for (int s = 128; s > 0; s >>= 1) {
        if (threadIdx.x < s) {
            rmn[threadIdx.x] = fminf(rmn[threadIdx.x], rmn[threadIdx.x + s]);
            rmx[threadIdx.x] = fmaxf(rmx[threadIdx.x], rmx[threadIdx.x + s]);
        }
        __syncthreads();
    }
    if (threadIdx.x == 0) { pmn[p] = rmn[0]; pmx[p] = rmx[0]; }
}

// ---------- K2: segmented row prefix in place (897th block = prep) ----------
__global__ void k_rowsum(float* __restrict__ S, const float* __restrict__ kap,
                         const float* __restrict__ pmn, const float* __restrict__ pmx,
                         float* __restrict__ xmn, float* __restrict__ xiv,
                         float* __restrict__ dcs, float* __restrict__ sq) {
    int p = blockIdx.x;
    if (p == 896) {                             // prep block
        int t = threadIdx.x;
        for (int k = t; k < 2048; k += 256) sq[k] = 0.f;
        if (t < 16) {
            float mn = 3.4e38f, mx = -3.4e38f;
            for (int k = 0; k < 56; k++) {
                mn = fminf(mn, pmn[t * 56 + k]);
                mx = fmaxf(mx, pmx[t * 56 + k]);
            }
            xmn[t] = mn;
            xiv[t] = 1.f / (mx - mn + 1e-7f);
        } else if (t == 32) kappa_consts(kap, dcs);
        return;
    }
    int b = p / 56, i = (p % 56) + 1;
    int c = threadIdx.x & 127, seg = threadIdx.x >> 7;
    int rowbase = b * SB + i * RS + c;
    __shared__ float tot[128];
    float v[28];
    if (seg == 0) {
        S[rowbase] = 0.f;                       // guard col j=0
        float acc = 0.f;
#pragma unroll
        for (int k = 0; k < 28; k++) {
            acc += S[rowbase + (k + 1) * 128];
            S[rowbase + (k + 1) * 128] = acc;
        }
        tot[c] = acc;
    } else {
        float acc = 0.f;
#pragma unroll
        for (int k = 0; k < 28; k++) {
            acc += S[rowbase + (29 + k) * 128];
            v[k] = acc;
        }
    }
    __syncthreads();
    if (seg == 1) {
        float base = tot[c];
#pragma unroll
        for (int k = 0; k < 28; k++) S[rowbase + (29 + k) * 128] = base + v[k];
    }
}

// ---------- K3: gather (log2 units) + packed A/B emit + squeeze ----------
struct ScaleU { int rb1, rb0; float xmch; };

__global__ void k_gather(const float* __restrict__ S, const float* __restrict__ x,
                         const float* __restrict__ gam, const float* __restrict__ bet,
                         const float* __restrict__ bnm, const float* __restrict__ bnv,
                         const float* __restrict__ xmn, const float* __restrict__ xiv,
                         const float* __restrict__ dcs, float* __restrict__ sq,
                         unsigned int* __restrict__ ABu) {
    int p_ = blockIdx.x;                        // 3584 blocks, XCD slab swizzle
    int L  = (p_ & 7) * 448 + (p_ >> 3);
    int b = L / 224, rem = L % 224;
    int i = rem >> 2, q = rem & 3;
    int c = threadIdx.x & 127, half = threadIdx.x >> 7;
    const float* sp = S + b * SB + c;
    float g = gam[c], be = bet[c], bm = bnm[c];
    float rs = rsqrtf(bnv[c] + 1e-3f);
    float xm = xmn[b], xi = xiv[b];
    float xmxi = xm * xi;
    // BN+sigmoid folded: sbn = rcp(1 + exp2(C1*w2 + C0)); alphas = w2*0.1
    float A1 = g * rs, A0 = be - g * bm * rs;
    float C1 = -A1 * (LOG2E * 0.1f);
    float C0 = -A0 * LOG2E;
    float d0 = dcs[0], d1 = dcs[1], d2 = dcs[2], d3 = dcs[3], d4 = dcs[4], nd = dcs[5];

    auto mkU = [&](int hk) {
        ScaleU u;
        int y1g = min(i + hk, HH - 1) + 1;
        int y0g = max(i - hk + 1, 0);
        u.rb1 = y1g * RS; u.rb0 = y0g * RS;
        u.xmch = xm * (float)(y1g - y0g);
        return u;
    };
    ScaleU u0 = mkU(1), u1 = mkU(2), u2 = mkU(4), u3 = mkU(8), u4 = mkU(16);

    // log2 of the measure (scale-invariant cos; alphas handled via *0.1)
    auto meas = [&](int j, const ScaleU& u, int hk) -> float {
        int x1g = min(j + hk, WW - 1) + 1;
        int x0g = max(j - hk + 1, 0);
        float cw = (float)(x1g - x0g);
        int o1 = x1g << 7, o0 = x0g << 7;
        float s = sp[u.rb1 + o1] - sp[u.rb0 + o1] - sp[u.rb1 + o0] + sp[u.rb0 + o0];
        return __log2f(fmaxf((s - u.xmch * cw) * xi, 0.f) + 1e-7f);
    };

    float asum = 0.f;
    int j0 = q * 14 + half * 7;
    for (int jj = 0; jj < 7; jj++) {
        int j = j0 + jj;
        float l0 = meas(j, u0, 1);
        float l1 = meas(j, u1, 2);
        float l2 = meas(j, u2, 4);
        float l3 = meas(j, u3, 8);
        float l4 = meas(j, u4, 16);
        float w2 = -2.f * l0 - l1 + l3 + 2.f * l4;
        asum += w2;
        float alphas = w2 * 0.1f;
        float mean = 0.2f * (l0 + l1 + l2 + l3 + l4);
        float a0 = l0 - mean, a1 = l1 - mean, a2 = l2 - mean, a3 = l3 - mean, a4 = l4 - mean;
        float na2  = a0 * a0 + a1 * a1 + a2 * a2 + a3 * a3 + a4 * a4;
        float adot = a0 * d0 + a1 * d1 + a2 * d2 + a3 * d3 + a4 * d4;
        float na = __builtin_amdgcn_sqrtf(na2);
        float cosv = (alphas * adot) * __builtin_amdgcn_rcpf(na * fabsf(alphas) * nd + 1e-7f);
        float sim = 0.5f * (cosv + 1.f);
        float sbn = __builtin_amdgcn_rcpf(1.f + exp2f(C1 * w2 + C0));
        int idx = b * NPERB + i * 7168 + j * 128 + c;
        float xs = fmaf(x[idx], xi, -xmxi);
        float A = sim * sbn;
        float B = (1.f - sim) * xs;
        __half2 h2 = __floats2half2_rn(A, B);
        ABu[idx] = __builtin_bit_cast(unsigned int, h2);
    }
    asum *= 0.1f;                               // alphas units
    __shared__ float red[256];
    red[threadIdx.x] = asum;
    __syncthreads();
    if (threadIdx.x < 128)
        atomicAdd(&sq[b * 128 + threadIdx.x], red[threadIdx.x] + red[threadIdx.x + 128]);
}

// ---------- K4: fused SE + mix (grid-strided, SE redundant per block) ----------
__launch_bounds__(256)
__global__ void k_mix(const unsigned int* __restrict__ ABu, const float* __restrict__ sq,
                      const float* __restrict__ W1, const float* __restrict__ b1,
                      const float* __restrict__ W2, const float* __restrict__ b2,
                      float* __restrict__ out) {
    __shared__ float buf[2048];
    __shared__ float hid[256];
    int tid = threadIdx.x;
    for (int k = tid; k < 2048; k += 256) buf[k] = sq[k] * (1.f / 3136.f);
    __syncthreads();
    {
        int bb = tid >> 4, h = tid & 15;
        float acc = b1[h];
        for (int c2 = 0; c2 < 128; c2++) acc += buf[bb * 128 + c2] * W1[c2 * 16 + h];
        hid[bb * 16 + h] = fmaxf(acc, 0.f);
    }
    __syncthreads();
    for (int k = tid; k < 2048; k += 256) {
        int bb = k >> 7, c2 = k & 127;
        float acc = b2[c2];
#pragma unroll
        for (int h = 0; h < 16; h++) acc += hid[bb * 16 + h] * W2[h * 128 + c2];
        buf[k] = sigmoidf_fast(acc);            // excite, overwrites squeeze copy
    }
    __syncthreads();
    for (int t = blockIdx.x * 256 + tid; t < NTOT / 4; t += 1024 * 256) {
        int flat = t * 4;
        int b = flat / NPERB, cb = flat & 127;
        uint4 u = ((const uint4*)ABu)[t];
        float2 p0 = __half22float2(__builtin_bit_cast(__half2, u.x));
        float2 p1 = __half22float2(__builtin_bit_cast(__half2, u.y));
        float2 p2 = __half22float2(__builtin_bit_cast(__half2, u.z));
        float2 p3 = __half22float2(__builtin_bit_cast(__half2, u.w));
        ((float4*)out)[t] = make_float4(p0.x + p0.y * buf[b * 128 + cb],
                                        p1.x + p1.y * buf[b * 128 + cb + 1],
                                        p2.x + p2.y * buf[b * 128 + cb + 2],
                                        p3.x + p3.y * buf[b * 128 + cb + 3]);
    }
}

extern "C" void kernel_launch(void* const* d_in, const int* in_sizes, int n_in,
                              void* d_out, int out_size, void* d_ws, size_t ws_size,
                              hipStream_t stream) {
    const float* x   = (const float*)d_in[0];
    const float* kap = (const float*)d_in[1];
    const float* W1  = (const float*)d_in[2];
    const float* b1  = (const float*)d_in[3];
    const float* W2  = (const float*)d_in[4];
    const float* b2  = (const float*)d_in[5];
    const float* gam = (const float*)d_in[6];
    const float* bet = (const float*)d_in[7];
    const float* bnm = (const float*)d_in[8];
    const float* bnv = (const float*)d_in[9];
    float* out = (float*)d_out;

    float*        S   = (float*)d_ws;                   // 16*SB guarded SAT
    unsigned int* ABu = (unsigned int*)(S + 16 * SB);   // NTOT u32 (half2 A,B)
    float* sq  = (float*)(ABu + NTOT);                  // 2048
    float* pmn = sq + 2048;                             // 896 -> 1024
    float* pmx = pmn + 1024;                            // 1024
    float* xmn = pmx + 1024;                            // 16
    float* xiv = xmn + 16;                              // 16
    float* dcs = xiv + 16;                              // 8

    k_colsum<<<896, 256, 0, stream>>>(x, S, pmn, pmx);
    k_rowsum<<<897, 256, 0, stream>>>(S, kap, pmn, pmx, xmn, xiv, dcs, sq);
    k_gather<<<3584, 256, 0, stream>>>(S, x, gam, bet, bnm, bnv, xmn, xiv, dcs, sq, ABu);
    k_mix<<<1024, 256, 0, stream>>>(ABu, sq, W1, b1, W2, b2, out);
}